// Round 9
// baseline (738.594 us; speedup 1.0000x reference)
//
#include <hip/hip_runtime.h>

typedef float vf2  __attribute__((ext_vector_type(2)));
typedef float v128f __attribute__((ext_vector_type(128)));

__device__ __forceinline__ vf2 cmulv(vf2 a, vf2 b){
  vf2 br; br.x = -b.y; br.y = b.x;
  return a.x*b + a.y*br;
}

// merged-diagonal angle for wire j of diagonal d (wave-uniform); d, j compile-time
#define ALPHA(d, j) (((d) & 1) \
  ? (W[((((d)>>1)*2+1)*12+(j))*3+0] + W[((((d)>>1)*2+0)*12+(j))*3+2]) \
  : (W[((((d)>>1)*2+0)*12+(j))*3+0] + xr[(j)] + W[(((((d)>>1)-1)*2+1)*12+(j))*3+2]))

// 6 RY gates on the reg-domain bits of the big-vector state (sl, par may be runtime)
#define GATES6(sl, par) do{ \
  _Pragma("unroll") \
  for (int lb = 0; lb < 6; lb++){ \
    const int wire_ = (par) ? (5 - lb) : (11 - lb); \
    vf2 cs_ = scsl[(sl)*12 + wire_]; \
    const float c_ = cs_.x, sn_ = cs_.y; \
    _Pragma("unroll") \
    for (int w0 = 0; w0 < 64; w0++){ \
      if (w0 & (1 << lb)) continue; \
      const int w1 = w0 | (1 << lb); \
      vf2 a_, b_, r0_, r1_; \
      a_.x = st[2*w0]; a_.y = st[2*w0+1]; \
      b_.x = st[2*w1]; b_.y = st[2*w1+1]; \
      r0_ = c_*a_ - sn_*b_; \
      r1_ = sn_*a_ + c_*b_; \
      st[2*w0] = r0_.x; st[2*w0+1] = r0_.y; \
      st[2*w1] = r1_.x; st[2*w1+1] = r1_.y; \
    } \
  } \
}while(0)

// 64x64 lane<->reg transpose through two XOR-swizzled 32x32 quadrant buffers
// (bufA = tbuf[0..1023], bufB = tbuf[1024..2047]).
// Quadrants (laneHalf,regHalf): B00,B01 (low lanes), B10,B11 (high lanes).
// new[u][w] = old[w][u]:  B00'=B00^T, B11'=B11^T, B01'=B10^T, B10'=B01^T.
// ORDERING IS LOAD-BEARING: the low-lane region must run BEFORE the high-lane
// region (T4 reads B10 before T5 overwrites bufB; T6a reads B01 after T3
// writes bufA). Cross-lane LDS deps between arms of a divergent if/else are
// INVISIBLE to the compiler (thread-local semantics) and the backend may
// emit the arms in either order (R8 failure). Hence: two sequential guarded
// ifs + memory-clobber fences to pin program order; within a region the
// wave's in-order LDS pipe + may-alias conservatism give correctness.
#define TRANSPOSE() do{ \
  const int qoff_ = (u < 32) ? 0 : 1024; \
  const int ul_ = u & 31; \
  _Pragma("unroll") /* T1: all lanes save regs 0..31 (B00->A, B10->B) */ \
  for (int w = 0; w < 32; w++){ \
    vf2 t_; t_.x = st[2*w]; t_.y = st[2*w+1]; \
    tbuf[qoff_ + (ul_ << 5) + ((w ^ ul_) & 31)] = t_; \
  } \
  asm volatile("" ::: "memory"); \
  if (u < 32){ \
    _Pragma("unroll") /* T2: new regs 0..31 = B00^T (from A) */ \
    for (int w = 0; w < 32; w++){ \
      vf2 t_ = tbuf[(w << 5) + ((ul_ ^ w) & 31)]; \
      st[2*w] = t_.x; st[2*w+1] = t_.y; \
    } \
    _Pragma("unroll") /* T3: save old regs 32..63 (B01 -> A) */ \
    for (int w = 0; w < 32; w++){ \
      vf2 t_; t_.x = st[2*(w+32)]; t_.y = st[2*(w+32)+1]; \
      tbuf[(ul_ << 5) + ((w ^ ul_) & 31)] = t_; \
    } \
    _Pragma("unroll") /* T4: new regs 32..63 = B10^T (from B) */ \
    for (int w = 0; w < 32; w++){ \
      vf2 t_ = tbuf[1024 + (w << 5) + ((ul_ ^ w) & 31)]; \
      st[2*(w+32)] = t_.x; st[2*(w+32)+1] = t_.y; \
    } \
  } \
  asm volatile("" ::: "memory"); \
  if (u >= 32){ \
    _Pragma("unroll") /* T5: save old regs 32..63 (B11 -> B) */ \
    for (int w = 0; w < 32; w++){ \
      vf2 t_; t_.x = st[2*(w+32)]; t_.y = st[2*(w+32)+1]; \
      tbuf[1024 + (ul_ << 5) + ((w ^ ul_) & 31)] = t_; \
    } \
    _Pragma("unroll") /* T6a: new regs 0..31 = B01^T (from A) */ \
    for (int w = 0; w < 32; w++){ \
      vf2 t_ = tbuf[(w << 5) + ((ul_ ^ w) & 31)]; \
      st[2*w] = t_.x; st[2*w+1] = t_.y; \
    } \
    _Pragma("unroll") /* T6b: new regs 32..63 = B11^T (from B) */ \
    for (int w = 0; w < 32; w++){ \
      vf2 t_ = tbuf[1024 + (w << 5) + ((ul_ ^ w) & 31)]; \
      st[2*(w+32)] = t_.x; st[2*(w+32)+1] = t_.y; \
    } \
  } \
  asm volatile("" ::: "memory"); \
}while(0)

// merged diagonal d (runtime): reg part from tabs (LDS), lane part from lp regs.
// Both arms are per-lane pure math (no cross-lane comm) -> divergence-safe.
#define DIAG(d, par) do{ \
  vf2 lp_ = (d)==1 ? lp1v : ((d)==2 ? lp2v : ((d)==3 ? lp3v : ((d)==4 ? lp4v : lp5v))); \
  vf2 lpn_ = -lp_; \
  const int u0_ = u & 1, u1_ = (u >> 1) & 1, u4_ = (u >> 4) & 1, u5_ = (u >> 5) & 1; \
  if (par){ \
    _Pragma("unroll") \
    for (int w = 0; w < 64; w++){ \
      vf2 dph_ = tabs[(d)-1][w]; \
      int sx_ = ((w & 1) * u5_) ^ (((w >> 5) & 1) * u0_); \
      vf2 a_; a_.x = st[2*w]; a_.y = st[2*w+1]; \
      vf2 t_ = cmulv(a_, dph_); \
      vf2 r_ = cmulv(t_, sx_ ? lpn_ : lp_); \
      st[2*w] = r_.x; st[2*w+1] = r_.y; \
    } \
  } else { \
    _Pragma("unroll") \
    for (int w = 0; w < 64; w++){ \
      vf2 dph_ = tabs[(d)-1][w]; \
      int sx_ = (((w >> 5) & 1) * u1_) ^ (((w >> 4) & 1) * u0_) \
              ^ (((w >> 1) & 1) * u5_) ^ ((w & 1) * u4_); \
      vf2 a_; a_.x = st[2*w]; a_.y = st[2*w+1]; \
      vf2 t_ = cmulv(a_, dph_); \
      vf2 r_ = cmulv(t_, sx_ ? lpn_ : lp_); \
      st[2*w] = r_.x; st[2*w+1] = r_.y; \
    } \
  } \
}while(0)

__global__ __attribute__((amdgpu_flat_work_group_size(64,64)))
__attribute__((amdgpu_waves_per_eu(2)))
void qiddm_wave(const float* __restrict__ gx,
                const float* __restrict__ gcw,
                const float* __restrict__ gcb,
                const float* __restrict__ gw1,
                const float* __restrict__ glw,
                const float* __restrict__ glb,
                float* __restrict__ gout)
{
  // One wave per sample; 4096-amp state in ONE ext_vector (mem2reg-guaranteed).
  // L0: lane u = idx bits 11..6 (wires 0..5), reg w = idx bits 5..0 (wires 6..11)
  // L1: lane u = idx bits 5..0,  reg w = idx bits 11..6
  // LDS = 16384 + 2560 + 576 = 19520 B -> 8 blocks/CU = 2 waves/SIMD.
  __shared__ vf2 tbuf[2048];        // quadrant transpose buffers (aliases conv image)
  __shared__ vf2 tabs[5][64];       // reg-domain diagonal tables
  __shared__ vf2 scsl[72];          // (cos, sin) of theta/2 per (sublayer, wire)

  const int u = threadIdx.x;        // lane 0..63
  const int bid = blockIdx.x;

  float xr[12];                     // circuit inputs / expvals (constant-indexed only)
  vf2 lp1v, lp2v, lp3v, lp4v, lp5v; // lane-domain diagonal factors (registers)

  // ---------- conv 3x3 s2 p1 + bias + GAP ----------
  {
    float* img = (float*)tbuf;
#pragma unroll
    for (int i = 0; i < 4; i++){
      float4 q4 = ((const float4*)gx)[(size_t)bid * 256 + i * 64 + u];
      ((float4*)img)[i * 64 + u] = q4;
    }
    float p[4][9];
#pragma unroll
    for (int i = 0; i < 4; i++){
      int pos = u + 64 * i, oi = pos >> 4, oj = pos & 15;
#pragma unroll
      for (int ki = 0; ki < 3; ki++)
#pragma unroll
        for (int kj = 0; kj < 3; kj++){
          int ri = 2*oi - 1 + ki, cj = 2*oj - 1 + kj;
          p[i][ki*3+kj] = (ri >= 0 && ri < 32 && cj >= 0 && cj < 32) ? img[ri*32+cj] : 0.0f;
        }
    }
#pragma unroll
    for (int q = 0; q < 12; q++){
      float a = 0.0f;
#pragma unroll
      for (int e = 0; e < 9; e++){
        float wv = gcw[q*9+e];                  // uniform -> scalarized
#pragma unroll
        for (int i = 0; i < 4; i++) a += p[i][e] * wv;
      }
#pragma unroll
      for (int off = 32; off; off >>= 1) a += __shfl_xor(a, off);
      xr[q] = gcb[q] + a * (1.0f/256.0f);
    }
  }

#pragma unroll 1
  for (int n = 0; n < 2; n++){
    const float* W = gw1 + n * 216;

    // ---- RY cos/sin table (72 gates) ----
#pragma unroll
    for (int rep = 0; rep < 2; rep++){
      int e = u + rep * 64;
      if (e < 72){
        float sv, cv; __sincosf(0.5f * W[e*3+1], &sv, &cv);
        vf2 cs; cs.x = cv; cs.y = sv; scsl[e] = cs;
      }
    }

    // ---- diagonal tables: reg-domain -> LDS tabs, lane-domain -> lp regs ----
#pragma unroll
    for (int d = 1; d <= 5; d++){
      const int par = d & 1;                    // 1 -> applied in L1 (r=1), 0 -> L0 (r=2)
      const int r = par ? 1 : 2;
      {
        float ph = 0.0f;
#pragma unroll
        for (int lb = 0; lb < 6; lb++){
          int wire = par ? (5 - lb) : (11 - lb);          // reg-domain wires
          ph += ALPHA(d, wire) * ((float)((u >> lb) & 1) - 0.5f);
        }
        int idx_r = par ? (u << 6) : u;
        int y = ((idx_r << r) | (idx_r >> (12 - r))) & 0xFFF;
        int s = __popc(idx_r & y) & 1;                    // within-reg CZ parity
        float sv, cv; __sincosf(ph, &sv, &cv);
        vf2 e_; e_.x = cv; e_.y = sv; if (s) e_ = -e_;
        tabs[d-1][u] = e_;
      }
      {
        float ph = 0.0f;
#pragma unroll
        for (int lb = 0; lb < 6; lb++){
          int wire = par ? (11 - lb) : (5 - lb);          // lane-domain wires
          ph += ALPHA(d, wire) * ((float)((u >> lb) & 1) - 0.5f);
        }
        int idx_l = par ? u : (u << 6);
        int y = ((idx_l << r) | (idx_l >> (12 - r))) & 0xFFF;
        int s = __popc(idx_l & y) & 1;                    // within-lane CZ parity
        float sv, cv; __sincosf(ph, &sv, &cv);
        vf2 e_; e_.x = cv; e_.y = sv; if (s) e_ = -e_;
        if      (d == 1) lp1v = e_;
        else if (d == 2) lp2v = e_;
        else if (d == 3) lp3v = e_;
        else if (d == 4) lp4v = e_;
        else             lp5v = e_;
      }
    }

    // ---- circuit: |0>, 12 half-sublayer steps, measure ----
    v128f st;
#pragma unroll
    for (int w = 0; w < 64; w++){ st[2*w] = 0.f; st[2*w+1] = 0.f; }
    if (u == 0) st[0] = 1.f;                    // idx 0 = (lane 0, reg 0)

    GATES6(0, 0);                               // k=0: s0 on wires 6..11 (L0)
#pragma unroll 1
    for (int k = 1; k < 12; k++){
      const int sl  = k >> 1;
      const int par = ((k + 1) >> 1) & 1;
      if (k & 1) TRANSPOSE();                   // flip lane/reg domains
      else       DIAG(sl, par);                 // D_sl before the sublayer's 2nd half
      GATES6(sl, par);
    }

    // ---- measurement in L0 (final omega-diagonal is a pure phase: dropped) ----
    {
      float P = 0.f, mm[6] = {0.f,0.f,0.f,0.f,0.f,0.f};  // wires 6..11 (reg bits 5..0)
#pragma unroll
      for (int w = 0; w < 64; w++){
        float re = st[2*w], im = st[2*w+1];
        float pr = re*re + im*im;
        P += pr;
#pragma unroll
        for (int i = 0; i < 6; i++)
          mm[i] += ((w >> (5 - i)) & 1) ? -pr : pr;
      }
#pragma unroll
      for (int q = 0; q < 12; q++){
        float val = (q < 6) ? (((u >> (5 - q)) & 1) ? -P : P)   // wires 0..5 (lane bits)
                            : mm[q - 6];
#pragma unroll
        for (int off = 32; off; off >>= 1) val += __shfl_xor(val, off);
        xr[q] = val;                            // uniform across lanes after butterfly
      }
    }
  }

  // ---------- final linear ----------
  {
#pragma unroll
    for (int i = 0; i < 16; i++){
      int o = i * 64 + u;
      const float4* wr = (const float4*)(glw + o * 12);   // 48B rows, 16B aligned
      float4 w0 = wr[0], w1 = wr[1], w2 = wr[2];
      float a = glb[o];
      a += xr[0]*w0.x + xr[1]*w0.y + xr[2]*w0.z + xr[3]*w0.w;
      a += xr[4]*w1.x + xr[5]*w1.y + xr[6]*w1.z + xr[7]*w1.w;
      a += xr[8]*w2.x + xr[9]*w2.y + xr[10]*w2.z + xr[11]*w2.w;
      gout[(size_t)bid * 1024 + o] = a;
    }
  }
}

extern "C" void kernel_launch(void* const* d_in, const int* in_sizes, int n_in,
                              void* d_out, int out_size, void* d_ws, size_t ws_size,
                              hipStream_t stream)
{
  (void)n_in; (void)d_ws; (void)ws_size; (void)out_size;
  const float* x  = (const float*)d_in[0];
  const float* cw = (const float*)d_in[1];
  const float* cb = (const float*)d_in[2];
  const float* w1 = (const float*)d_in[3];
  const float* lw = (const float*)d_in[4];
  const float* lb = (const float*)d_in[5];
  float* out = (float*)d_out;
  const int nb = in_sizes[0] / 1024;   // 2048 samples, one wave each
  hipLaunchKernelGGL(qiddm_wave, dim3(nb), dim3(64), 0, stream,
                     x, cw, cb, w1, lw, lb, out);
}

// Round 10
// 736.345 us; speedup vs baseline: 1.0031x; 1.0031x over previous
//
#include <hip/hip_runtime.h>

typedef float vf2  __attribute__((ext_vector_type(2)));
typedef float v128f __attribute__((ext_vector_type(128)));

__device__ __forceinline__ vf2 cmulv(vf2 a, vf2 b){
  vf2 br; br.x = -b.y; br.y = b.x;
  return a.x*b + a.y*br;
}

// merged-diagonal angle for wire j of diagonal d (wave-uniform); d, j compile-time
#define ALPHA(d, j) (((d) & 1) \
  ? (W[((((d)>>1)*2+1)*12+(j))*3+0] + W[((((d)>>1)*2+0)*12+(j))*3+2]) \
  : (W[((((d)>>1)*2+0)*12+(j))*3+0] + xr[(j)] + W[(((((d)>>1)-1)*2+1)*12+(j))*3+2]))

// 6 RY gates on the reg-domain bits of the big-vector state (sl, par may be runtime)
#define GATES6(sl, par) do{ \
  _Pragma("unroll") \
  for (int lb = 0; lb < 6; lb++){ \
    const int wire_ = (par) ? (5 - lb) : (11 - lb); \
    vf2 cs_ = scsl[(sl)*12 + wire_]; \
    const float c_ = cs_.x, sn_ = cs_.y; \
    _Pragma("unroll") \
    for (int w0 = 0; w0 < 64; w0++){ \
      if (w0 & (1 << lb)) continue; \
      const int w1 = w0 | (1 << lb); \
      vf2 a_, b_, r0_, r1_; \
      a_.x = st[2*w0]; a_.y = st[2*w0+1]; \
      b_.x = st[2*w1]; b_.y = st[2*w1+1]; \
      r0_ = c_*a_ - sn_*b_; \
      r1_ = sn_*a_ + c_*b_; \
      st[2*w0] = r0_.x; st[2*w0+1] = r0_.y; \
      st[2*w1] = r1_.x; st[2*w1+1] = r1_.y; \
    } \
  } \
}while(0)

// 64x64 lane<->reg transpose through two XOR-swizzled 32x32 quadrant buffers
// (bufA = tbuf[0..1023], bufB = tbuf[1024..2047]).
// Quadrants (laneHalf,regHalf): B00,B01 (low lanes), B10,B11 (high lanes).
// new[u][w] = old[w][u]:  B00'=B00^T, B11'=B11^T, B01'=B10^T, B10'=B01^T.
// ORDERING IS LOAD-BEARING: low-lane region BEFORE high-lane region (T4 reads
// B10 before T5 overwrites bufB; T6a reads B01 after T3 writes bufA).
// Divergent if/else arms have NO compiler-visible cross-lane deps (R8 failed);
// sequential guarded ifs + memory-clobber fences pin program order.
#define TRANSPOSE() do{ \
  const int qoff_ = (u < 32) ? 0 : 1024; \
  const int ul_ = u & 31; \
  _Pragma("unroll") /* T1: all lanes save regs 0..31 (B00->A, B10->B) */ \
  for (int w = 0; w < 32; w++){ \
    vf2 t_; t_.x = st[2*w]; t_.y = st[2*w+1]; \
    tbuf[qoff_ + (ul_ << 5) + ((w ^ ul_) & 31)] = t_; \
  } \
  asm volatile("" ::: "memory"); \
  if (u < 32){ \
    _Pragma("unroll") /* T2: new regs 0..31 = B00^T (from A) */ \
    for (int w = 0; w < 32; w++){ \
      vf2 t_ = tbuf[(w << 5) + ((ul_ ^ w) & 31)]; \
      st[2*w] = t_.x; st[2*w+1] = t_.y; \
    } \
    _Pragma("unroll") /* T3: save old regs 32..63 (B01 -> A) */ \
    for (int w = 0; w < 32; w++){ \
      vf2 t_; t_.x = st[2*(w+32)]; t_.y = st[2*(w+32)+1]; \
      tbuf[(ul_ << 5) + ((w ^ ul_) & 31)] = t_; \
    } \
    _Pragma("unroll") /* T4: new regs 32..63 = B10^T (from B) */ \
    for (int w = 0; w < 32; w++){ \
      vf2 t_ = tbuf[1024 + (w << 5) + ((ul_ ^ w) & 31)]; \
      st[2*(w+32)] = t_.x; st[2*(w+32)+1] = t_.y; \
    } \
  } \
  asm volatile("" ::: "memory"); \
  if (u >= 32){ \
    _Pragma("unroll") /* T5: save old regs 32..63 (B11 -> B) */ \
    for (int w = 0; w < 32; w++){ \
      vf2 t_; t_.x = st[2*(w+32)]; t_.y = st[2*(w+32)+1]; \
      tbuf[1024 + (ul_ << 5) + ((w ^ ul_) & 31)] = t_; \
    } \
    _Pragma("unroll") /* T6a: new regs 0..31 = B01^T (from A) */ \
    for (int w = 0; w < 32; w++){ \
      vf2 t_ = tbuf[(w << 5) + ((ul_ ^ w) & 31)]; \
      st[2*w] = t_.x; st[2*w+1] = t_.y; \
    } \
    _Pragma("unroll") /* T6b: new regs 32..63 = B11^T (from B) */ \
    for (int w = 0; w < 32; w++){ \
      vf2 t_ = tbuf[1024 + (w << 5) + ((ul_ ^ w) & 31)]; \
      st[2*(w+32)] = t_.x; st[2*(w+32)+1] = t_.y; \
    } \
  } \
  asm volatile("" ::: "memory"); \
}while(0)

// merged diagonal d (runtime): reg part from tabs (LDS), lane part from lp regs.
// Both arms are per-lane pure math (no cross-lane comm) -> divergence-safe.
#define DIAG(d, par) do{ \
  vf2 lp_ = (d)==1 ? lp1v : ((d)==2 ? lp2v : ((d)==3 ? lp3v : ((d)==4 ? lp4v : lp5v))); \
  vf2 lpn_ = -lp_; \
  const int u0_ = u & 1, u1_ = (u >> 1) & 1, u4_ = (u >> 4) & 1, u5_ = (u >> 5) & 1; \
  if (par){ \
    _Pragma("unroll") \
    for (int w = 0; w < 64; w++){ \
      vf2 dph_ = tabs[(d)-1][w]; \
      int sx_ = ((w & 1) * u5_) ^ (((w >> 5) & 1) * u0_); \
      vf2 a_; a_.x = st[2*w]; a_.y = st[2*w+1]; \
      vf2 t_ = cmulv(a_, dph_); \
      vf2 r_ = cmulv(t_, sx_ ? lpn_ : lp_); \
      st[2*w] = r_.x; st[2*w+1] = r_.y; \
    } \
  } else { \
    _Pragma("unroll") \
    for (int w = 0; w < 64; w++){ \
      vf2 dph_ = tabs[(d)-1][w]; \
      int sx_ = (((w >> 5) & 1) * u1_) ^ (((w >> 4) & 1) * u0_) \
              ^ (((w >> 1) & 1) * u5_) ^ ((w & 1) * u4_); \
      vf2 a_; a_.x = st[2*w]; a_.y = st[2*w+1]; \
      vf2 t_ = cmulv(a_, dph_); \
      vf2 r_ = cmulv(t_, sx_ ? lpn_ : lp_); \
      st[2*w] = r_.x; st[2*w+1] = r_.y; \
    } \
  } \
}while(0)

__global__ __attribute__((amdgpu_flat_work_group_size(64,64)))
__attribute__((amdgpu_waves_per_eu(2, 2)))   // PIN both ends: max=2 stops the
// allocator spilling the 128-reg state to chase the 4-wave tier (R9: VGPR=128,
// 652MB scratch); min=2 keeps budget 256 >> ~170 demand. R7(min=1)=144 VGPR.
void qiddm_wave(const float* __restrict__ gx,
                const float* __restrict__ gcw,
                const float* __restrict__ gcb,
                const float* __restrict__ gw1,
                const float* __restrict__ glw,
                const float* __restrict__ glb,
                float* __restrict__ gout)
{
  // One wave per sample; 4096-amp state in ONE ext_vector (mem2reg-guaranteed).
  // L0: lane u = idx bits 11..6 (wires 0..5), reg w = idx bits 5..0 (wires 6..11)
  // L1: lane u = idx bits 5..0,  reg w = idx bits 11..6
  // LDS = 16384 + 2560 + 576 = 19520 B -> 8 blocks/CU = 2 waves/SIMD.
  __shared__ vf2 tbuf[2048];        // quadrant transpose buffers (aliases conv image)
  __shared__ vf2 tabs[5][64];       // reg-domain diagonal tables
  __shared__ vf2 scsl[72];          // (cos, sin) of theta/2 per (sublayer, wire)

  const int u = threadIdx.x;        // lane 0..63
  const int bid = blockIdx.x;

  float xr[12];                     // circuit inputs / expvals (constant-indexed only)
  vf2 lp1v, lp2v, lp3v, lp4v, lp5v; // lane-domain diagonal factors (registers)

  // ---------- conv 3x3 s2 p1 + bias + GAP ----------
  {
    float* img = (float*)tbuf;
#pragma unroll
    for (int i = 0; i < 4; i++){
      float4 q4 = ((const float4*)gx)[(size_t)bid * 256 + i * 64 + u];
      ((float4*)img)[i * 64 + u] = q4;
    }
    float p[4][9];
#pragma unroll
    for (int i = 0; i < 4; i++){
      int pos = u + 64 * i, oi = pos >> 4, oj = pos & 15;
#pragma unroll
      for (int ki = 0; ki < 3; ki++)
#pragma unroll
        for (int kj = 0; kj < 3; kj++){
          int ri = 2*oi - 1 + ki, cj = 2*oj - 1 + kj;
          p[i][ki*3+kj] = (ri >= 0 && ri < 32 && cj >= 0 && cj < 32) ? img[ri*32+cj] : 0.0f;
        }
    }
#pragma unroll
    for (int q = 0; q < 12; q++){
      float a = 0.0f;
#pragma unroll
      for (int e = 0; e < 9; e++){
        float wv = gcw[q*9+e];                  // uniform -> scalarized
#pragma unroll
        for (int i = 0; i < 4; i++) a += p[i][e] * wv;
      }
#pragma unroll
      for (int off = 32; off; off >>= 1) a += __shfl_xor(a, off);
      xr[q] = gcb[q] + a * (1.0f/256.0f);
    }
  }

#pragma unroll 1
  for (int n = 0; n < 2; n++){
    const float* W = gw1 + n * 216;

    // ---- RY cos/sin table (72 gates) ----
#pragma unroll
    for (int rep = 0; rep < 2; rep++){
      int e = u + rep * 64;
      if (e < 72){
        float sv, cv; __sincosf(0.5f * W[e*3+1], &sv, &cv);
        vf2 cs; cs.x = cv; cs.y = sv; scsl[e] = cs;
      }
    }

    // ---- diagonal tables: reg-domain -> LDS tabs, lane-domain -> lp regs ----
#pragma unroll
    for (int d = 1; d <= 5; d++){
      const int par = d & 1;                    // 1 -> applied in L1 (r=1), 0 -> L0 (r=2)
      const int r = par ? 1 : 2;
      {
        float ph = 0.0f;
#pragma unroll
        for (int lb = 0; lb < 6; lb++){
          int wire = par ? (5 - lb) : (11 - lb);          // reg-domain wires
          ph += ALPHA(d, wire) * ((float)((u >> lb) & 1) - 0.5f);
        }
        int idx_r = par ? (u << 6) : u;
        int y = ((idx_r << r) | (idx_r >> (12 - r))) & 0xFFF;
        int s = __popc(idx_r & y) & 1;                    // within-reg CZ parity
        float sv, cv; __sincosf(ph, &sv, &cv);
        vf2 e_; e_.x = cv; e_.y = sv; if (s) e_ = -e_;
        tabs[d-1][u] = e_;
      }
      {
        float ph = 0.0f;
#pragma unroll
        for (int lb = 0; lb < 6; lb++){
          int wire = par ? (11 - lb) : (5 - lb);          // lane-domain wires
          ph += ALPHA(d, wire) * ((float)((u >> lb) & 1) - 0.5f);
        }
        int idx_l = par ? u : (u << 6);
        int y = ((idx_l << r) | (idx_l >> (12 - r))) & 0xFFF;
        int s = __popc(idx_l & y) & 1;                    // within-lane CZ parity
        float sv, cv; __sincosf(ph, &sv, &cv);
        vf2 e_; e_.x = cv; e_.y = sv; if (s) e_ = -e_;
        if      (d == 1) lp1v = e_;
        else if (d == 2) lp2v = e_;
        else if (d == 3) lp3v = e_;
        else if (d == 4) lp4v = e_;
        else             lp5v = e_;
      }
    }

    // ---- circuit: |0>, 12 half-sublayer steps, measure ----
    v128f st;
#pragma unroll
    for (int w = 0; w < 64; w++){ st[2*w] = 0.f; st[2*w+1] = 0.f; }
    if (u == 0) st[0] = 1.f;                    // idx 0 = (lane 0, reg 0)

    GATES6(0, 0);                               // k=0: s0 on wires 6..11 (L0)
#pragma unroll 1
    for (int k = 1; k < 12; k++){
      const int sl  = k >> 1;
      const int par = ((k + 1) >> 1) & 1;
      if (k & 1) TRANSPOSE();                   // flip lane/reg domains
      else       DIAG(sl, par);                 // D_sl before the sublayer's 2nd half
      GATES6(sl, par);
    }

    // ---- measurement in L0 (final omega-diagonal is a pure phase: dropped) ----
    {
      float P = 0.f, mm[6] = {0.f,0.f,0.f,0.f,0.f,0.f};  // wires 6..11 (reg bits 5..0)
#pragma unroll
      for (int w = 0; w < 64; w++){
        float re = st[2*w], im = st[2*w+1];
        float pr = re*re + im*im;
        P += pr;
#pragma unroll
        for (int i = 0; i < 6; i++)
          mm[i] += ((w >> (5 - i)) & 1) ? -pr : pr;
      }
#pragma unroll
      for (int q = 0; q < 12; q++){
        float val = (q < 6) ? (((u >> (5 - q)) & 1) ? -P : P)   // wires 0..5 (lane bits)
                            : mm[q - 6];
#pragma unroll
        for (int off = 32; off; off >>= 1) val += __shfl_xor(val, off);
        xr[q] = val;                            // uniform across lanes after butterfly
      }
    }
  }

  // ---------- final linear ----------
  {
#pragma unroll
    for (int i = 0; i < 16; i++){
      int o = i * 64 + u;
      const float4* wr = (const float4*)(glw + o * 12);   // 48B rows, 16B aligned
      float4 w0 = wr[0], w1 = wr[1], w2 = wr[2];
      float a = glb[o];
      a += xr[0]*w0.x + xr[1]*w0.y + xr[2]*w0.z + xr[3]*w0.w;
      a += xr[4]*w1.x + xr[5]*w1.y + xr[6]*w1.z + xr[7]*w1.w;
      a += xr[8]*w2.x + xr[9]*w2.y + xr[10]*w2.z + xr[11]*w2.w;
      gout[(size_t)bid * 1024 + o] = a;
    }
  }
}

extern "C" void kernel_launch(void* const* d_in, const int* in_sizes, int n_in,
                              void* d_out, int out_size, void* d_ws, size_t ws_size,
                              hipStream_t stream)
{
  (void)n_in; (void)d_ws; (void)ws_size; (void)out_size;
  const float* x  = (const float*)d_in[0];
  const float* cw = (const float*)d_in[1];
  const float* cb = (const float*)d_in[2];
  const float* w1 = (const float*)d_in[3];
  const float* lw = (const float*)d_in[4];
  const float* lb = (const float*)d_in[5];
  float* out = (float*)d_out;
  const int nb = in_sizes[0] / 1024;   // 2048 samples, one wave each
  hipLaunchKernelGGL(qiddm_wave, dim3(nb), dim3(64), 0, stream,
                     x, cw, cb, w1, lw, lb, out);
}

// Round 11
// 244.307 us; speedup vs baseline: 3.0232x; 3.0140x over previous
//
#include <hip/hip_runtime.h>

typedef float vf2  __attribute__((ext_vector_type(2)));
typedef float v128f __attribute__((ext_vector_type(128)));

__device__ __forceinline__ vf2 cmulv(vf2 a, vf2 b){
  vf2 br; br.x = -b.y; br.y = b.x;
  return a.x*b + a.y*br;
}

// merged-diagonal angle for wire j of diagonal d (wave-uniform); d, j compile-time
#define ALPHA(d, j) (((d) & 1) \
  ? (W[((((d)>>1)*2+1)*12+(j))*3+0] + W[((((d)>>1)*2+0)*12+(j))*3+2]) \
  : (W[((((d)>>1)*2+0)*12+(j))*3+0] + xr[(j)] + W[(((((d)>>1)-1)*2+1)*12+(j))*3+2]))

// 6 RY gates on the reg-domain bits of the big-vector state (sl, par may be runtime)
#define GATES6(sl, par) do{ \
  _Pragma("unroll") \
  for (int lb = 0; lb < 6; lb++){ \
    const int wire_ = (par) ? (5 - lb) : (11 - lb); \
    vf2 cs_ = scsl[(sl)*12 + wire_]; \
    const float c_ = cs_.x, sn_ = cs_.y; \
    _Pragma("unroll") \
    for (int w0 = 0; w0 < 64; w0++){ \
      if (w0 & (1 << lb)) continue; \
      const int w1 = w0 | (1 << lb); \
      vf2 a_, b_, r0_, r1_; \
      a_.x = st[2*w0]; a_.y = st[2*w0+1]; \
      b_.x = st[2*w1]; b_.y = st[2*w1+1]; \
      r0_ = c_*a_ - sn_*b_; \
      r1_ = sn_*a_ + c_*b_; \
      st[2*w0] = r0_.x; st[2*w0+1] = r0_.y; \
      st[2*w1] = r1_.x; st[2*w1+1] = r1_.y; \
    } \
  } \
}while(0)

// 64x64 lane<->reg transpose through two XOR-swizzled 32x32 quadrant buffers
// (bufA = tbuf[0..1023], bufB = tbuf[1024..2047]).
// Quadrants (laneHalf,regHalf): B00,B01 (low lanes), B10,B11 (high lanes).
// new[u][w] = old[w][u]:  B00'=B00^T, B11'=B11^T, B01'=B10^T, B10'=B01^T.
// ORDERING IS LOAD-BEARING: low-lane region BEFORE high-lane region (T4 reads
// B10 before T5 overwrites bufB; T6a reads B01 after T3 writes bufA).
// Divergent if/else arms have NO compiler-visible cross-lane deps (R8 failed);
// sequential guarded ifs + memory-clobber fences pin program order.
#define TRANSPOSE() do{ \
  const int qoff_ = (u < 32) ? 0 : 1024; \
  const int ul_ = u & 31; \
  _Pragma("unroll") /* T1: all lanes save regs 0..31 (B00->A, B10->B) */ \
  for (int w = 0; w < 32; w++){ \
    vf2 t_; t_.x = st[2*w]; t_.y = st[2*w+1]; \
    tbuf[qoff_ + (ul_ << 5) + ((w ^ ul_) & 31)] = t_; \
  } \
  asm volatile("" ::: "memory"); \
  if (u < 32){ \
    _Pragma("unroll") /* T2: new regs 0..31 = B00^T (from A) */ \
    for (int w = 0; w < 32; w++){ \
      vf2 t_ = tbuf[(w << 5) + ((ul_ ^ w) & 31)]; \
      st[2*w] = t_.x; st[2*w+1] = t_.y; \
    } \
    _Pragma("unroll") /* T3: save old regs 32..63 (B01 -> A) */ \
    for (int w = 0; w < 32; w++){ \
      vf2 t_; t_.x = st[2*(w+32)]; t_.y = st[2*(w+32)+1]; \
      tbuf[(ul_ << 5) + ((w ^ ul_) & 31)] = t_; \
    } \
    _Pragma("unroll") /* T4: new regs 32..63 = B10^T (from B) */ \
    for (int w = 0; w < 32; w++){ \
      vf2 t_ = tbuf[1024 + (w << 5) + ((ul_ ^ w) & 31)]; \
      st[2*(w+32)] = t_.x; st[2*(w+32)+1] = t_.y; \
    } \
  } \
  asm volatile("" ::: "memory"); \
  if (u >= 32){ \
    _Pragma("unroll") /* T5: save old regs 32..63 (B11 -> B) */ \
    for (int w = 0; w < 32; w++){ \
      vf2 t_; t_.x = st[2*(w+32)]; t_.y = st[2*(w+32)+1]; \
      tbuf[1024 + (ul_ << 5) + ((w ^ ul_) & 31)] = t_; \
    } \
    _Pragma("unroll") /* T6a: new regs 0..31 = B01^T (from A) */ \
    for (int w = 0; w < 32; w++){ \
      vf2 t_ = tbuf[(w << 5) + ((ul_ ^ w) & 31)]; \
      st[2*w] = t_.x; st[2*w+1] = t_.y; \
    } \
    _Pragma("unroll") /* T6b: new regs 32..63 = B11^T (from B) */ \
    for (int w = 0; w < 32; w++){ \
      vf2 t_ = tbuf[1024 + (w << 5) + ((ul_ ^ w) & 31)]; \
      st[2*(w+32)] = t_.x; st[2*(w+32)+1] = t_.y; \
    } \
  } \
  asm volatile("" ::: "memory"); \
}while(0)

// merged diagonal d (runtime): reg part from tabs (LDS), lane part from lp regs.
// Both arms are per-lane pure math (no cross-lane comm) -> divergence-safe.
#define DIAG(d, par) do{ \
  vf2 lp_ = (d)==1 ? lp1v : ((d)==2 ? lp2v : ((d)==3 ? lp3v : ((d)==4 ? lp4v : lp5v))); \
  vf2 lpn_ = -lp_; \
  const int u0_ = u & 1, u1_ = (u >> 1) & 1, u4_ = (u >> 4) & 1, u5_ = (u >> 5) & 1; \
  if (par){ \
    _Pragma("unroll") \
    for (int w = 0; w < 64; w++){ \
      vf2 dph_ = tabs[(d)-1][w]; \
      int sx_ = ((w & 1) * u5_) ^ (((w >> 5) & 1) * u0_); \
      vf2 a_; a_.x = st[2*w]; a_.y = st[2*w+1]; \
      vf2 t_ = cmulv(a_, dph_); \
      vf2 r_ = cmulv(t_, sx_ ? lpn_ : lp_); \
      st[2*w] = r_.x; st[2*w+1] = r_.y; \
    } \
  } else { \
    _Pragma("unroll") \
    for (int w = 0; w < 64; w++){ \
      vf2 dph_ = tabs[(d)-1][w]; \
      int sx_ = (((w >> 5) & 1) * u1_) ^ (((w >> 4) & 1) * u0_) \
              ^ (((w >> 1) & 1) * u5_) ^ ((w & 1) * u4_); \
      vf2 a_; a_.x = st[2*w]; a_.y = st[2*w+1]; \
      vf2 t_ = cmulv(a_, dph_); \
      vf2 r_ = cmulv(t_, sx_ ? lpn_ : lp_); \
      st[2*w] = r_.x; st[2*w+1] = r_.y; \
    } \
  } \
}while(0)

__global__ __attribute__((amdgpu_flat_work_group_size(64,64)))
__attribute__((amdgpu_waves_per_eu(1)))
// min=1 is the ONLY proven no-spill config (R7: 144 VGPR, zero scratch).
// Any min>=2 makes the backend cap VGPRs at 128 and spill the 128-reg state
// (R9/R10: VGPR=128, 1.7 GB scratch traffic, 690 us). HW occupancy is
// resource-driven at dispatch: with LDS=19.5 KB (8 WG/CU) and total regs
// <=256, the hardware co-schedules 2 waves/SIMD regardless of this hint.
void qiddm_wave(const float* __restrict__ gx,
                const float* __restrict__ gcw,
                const float* __restrict__ gcb,
                const float* __restrict__ gw1,
                const float* __restrict__ glw,
                const float* __restrict__ glb,
                float* __restrict__ gout)
{
  // One wave per sample; 4096-amp state in ONE ext_vector (mem2reg-guaranteed).
  // L0: lane u = idx bits 11..6 (wires 0..5), reg w = idx bits 5..0 (wires 6..11)
  // L1: lane u = idx bits 5..0,  reg w = idx bits 11..6
  // LDS = 16384 + 2560 + 576 = 19520 B -> 8 blocks/CU possible = 2 waves/SIMD.
  __shared__ vf2 tbuf[2048];        // quadrant transpose buffers (aliases conv image)
  __shared__ vf2 tabs[5][64];       // reg-domain diagonal tables
  __shared__ vf2 scsl[72];          // (cos, sin) of theta/2 per (sublayer, wire)

  const int u = threadIdx.x;        // lane 0..63
  const int bid = blockIdx.x;

  float xr[12];                     // circuit inputs / expvals (constant-indexed only)
  vf2 lp1v, lp2v, lp3v, lp4v, lp5v; // lane-domain diagonal factors (registers)

  // ---------- conv 3x3 s2 p1 + bias + GAP ----------
  {
    float* img = (float*)tbuf;
#pragma unroll
    for (int i = 0; i < 4; i++){
      float4 q4 = ((const float4*)gx)[(size_t)bid * 256 + i * 64 + u];
      ((float4*)img)[i * 64 + u] = q4;
    }
    float p[4][9];
#pragma unroll
    for (int i = 0; i < 4; i++){
      int pos = u + 64 * i, oi = pos >> 4, oj = pos & 15;
#pragma unroll
      for (int ki = 0; ki < 3; ki++)
#pragma unroll
        for (int kj = 0; kj < 3; kj++){
          int ri = 2*oi - 1 + ki, cj = 2*oj - 1 + kj;
          p[i][ki*3+kj] = (ri >= 0 && ri < 32 && cj >= 0 && cj < 32) ? img[ri*32+cj] : 0.0f;
        }
    }
#pragma unroll
    for (int q = 0; q < 12; q++){
      float a = 0.0f;
#pragma unroll
      for (int e = 0; e < 9; e++){
        float wv = gcw[q*9+e];                  // uniform -> scalarized
#pragma unroll
        for (int i = 0; i < 4; i++) a += p[i][e] * wv;
      }
#pragma unroll
      for (int off = 32; off; off >>= 1) a += __shfl_xor(a, off);
      xr[q] = gcb[q] + a * (1.0f/256.0f);
    }
  }

#pragma unroll 1
  for (int n = 0; n < 2; n++){
    const float* W = gw1 + n * 216;

    // ---- RY cos/sin table (72 gates) ----
#pragma unroll
    for (int rep = 0; rep < 2; rep++){
      int e = u + rep * 64;
      if (e < 72){
        float sv, cv; __sincosf(0.5f * W[e*3+1], &sv, &cv);
        vf2 cs; cs.x = cv; cs.y = sv; scsl[e] = cs;
      }
    }

    // ---- diagonal tables: reg-domain -> LDS tabs, lane-domain -> lp regs ----
#pragma unroll
    for (int d = 1; d <= 5; d++){
      const int par = d & 1;                    // 1 -> applied in L1 (r=1), 0 -> L0 (r=2)
      const int r = par ? 1 : 2;
      {
        float ph = 0.0f;
#pragma unroll
        for (int lb = 0; lb < 6; lb++){
          int wire = par ? (5 - lb) : (11 - lb);          // reg-domain wires
          ph += ALPHA(d, wire) * ((float)((u >> lb) & 1) - 0.5f);
        }
        int idx_r = par ? (u << 6) : u;
        int y = ((idx_r << r) | (idx_r >> (12 - r))) & 0xFFF;
        int s = __popc(idx_r & y) & 1;                    // within-reg CZ parity
        float sv, cv; __sincosf(ph, &sv, &cv);
        vf2 e_; e_.x = cv; e_.y = sv; if (s) e_ = -e_;
        tabs[d-1][u] = e_;
      }
      {
        float ph = 0.0f;
#pragma unroll
        for (int lb = 0; lb < 6; lb++){
          int wire = par ? (11 - lb) : (5 - lb);          // lane-domain wires
          ph += ALPHA(d, wire) * ((float)((u >> lb) & 1) - 0.5f);
        }
        int idx_l = par ? u : (u << 6);
        int y = ((idx_l << r) | (idx_l >> (12 - r))) & 0xFFF;
        int s = __popc(idx_l & y) & 1;                    // within-lane CZ parity
        float sv, cv; __sincosf(ph, &sv, &cv);
        vf2 e_; e_.x = cv; e_.y = sv; if (s) e_ = -e_;
        if      (d == 1) lp1v = e_;
        else if (d == 2) lp2v = e_;
        else if (d == 3) lp3v = e_;
        else if (d == 4) lp4v = e_;
        else             lp5v = e_;
      }
    }

    // ---- circuit: |0>, 12 half-sublayer steps, measure ----
    v128f st;
#pragma unroll
    for (int w = 0; w < 64; w++){ st[2*w] = 0.f; st[2*w+1] = 0.f; }
    if (u == 0) st[0] = 1.f;                    // idx 0 = (lane 0, reg 0)

    GATES6(0, 0);                               // k=0: s0 on wires 6..11 (L0)
#pragma unroll 1
    for (int k = 1; k < 12; k++){
      const int sl  = k >> 1;
      const int par = ((k + 1) >> 1) & 1;
      if (k & 1) TRANSPOSE();                   // flip lane/reg domains
      else       DIAG(sl, par);                 // D_sl before the sublayer's 2nd half
      GATES6(sl, par);
    }

    // ---- measurement in L0 (final omega-diagonal is a pure phase: dropped) ----
    {
      float P = 0.f, mm[6] = {0.f,0.f,0.f,0.f,0.f,0.f};  // wires 6..11 (reg bits 5..0)
#pragma unroll
      for (int w = 0; w < 64; w++){
        float re = st[2*w], im = st[2*w+1];
        float pr = re*re + im*im;
        P += pr;
#pragma unroll
        for (int i = 0; i < 6; i++)
          mm[i] += ((w >> (5 - i)) & 1) ? -pr : pr;
      }
#pragma unroll
      for (int q = 0; q < 12; q++){
        float val = (q < 6) ? (((u >> (5 - q)) & 1) ? -P : P)   // wires 0..5 (lane bits)
                            : mm[q - 6];
#pragma unroll
        for (int off = 32; off; off >>= 1) val += __shfl_xor(val, off);
        xr[q] = val;                            // uniform across lanes after butterfly
      }
    }
  }

  // ---------- final linear ----------
  {
#pragma unroll
    for (int i = 0; i < 16; i++){
      int o = i * 64 + u;
      const float4* wr = (const float4*)(glw + o * 12);   // 48B rows, 16B aligned
      float4 w0 = wr[0], w1 = wr[1], w2 = wr[2];
      float a = glb[o];
      a += xr[0]*w0.x + xr[1]*w0.y + xr[2]*w0.z + xr[3]*w0.w;
      a += xr[4]*w1.x + xr[5]*w1.y + xr[6]*w1.z + xr[7]*w1.w;
      a += xr[8]*w2.x + xr[9]*w2.y + xr[10]*w2.z + xr[11]*w2.w;
      gout[(size_t)bid * 1024 + o] = a;
    }
  }
}

extern "C" void kernel_launch(void* const* d_in, const int* in_sizes, int n_in,
                              void* d_out, int out_size, void* d_ws, size_t ws_size,
                              hipStream_t stream)
{
  (void)n_in; (void)d_ws; (void)ws_size; (void)out_size;
  const float* x  = (const float*)d_in[0];
  const float* cw = (const float*)d_in[1];
  const float* cb = (const float*)d_in[2];
  const float* w1 = (const float*)d_in[3];
  const float* lw = (const float*)d_in[4];
  const float* lb = (const float*)d_in[5];
  float* out = (float*)d_out;
  const int nb = in_sizes[0] / 1024;   // 2048 samples, one wave each
  hipLaunchKernelGGL(qiddm_wave, dim3(nb), dim3(64), 0, stream,
                     x, cw, cb, w1, lw, lb, out);
}